// Round 3
// baseline (409.370 us; speedup 1.0000x reference)
//
#include <hip/hip_runtime.h>

typedef unsigned short ushort_t;

#define B_   4096
#define IN_  1024
#define H_   1024
#define F_   128
#define G4_  4096
#define EPS_ 1e-5f

__device__ __forceinline__ float us2f(unsigned short s) {
  union { unsigned int u; float f; } v;
  v.u = ((unsigned int)s) << 16;
  return v.f;
}
__device__ __forceinline__ float sigf(float x) { return 1.0f / (1.0f + __expf(-x)); }
__device__ __forceinline__ float tanh_f(float x) { return 1.0f - 2.0f / (1.0f + __expf(2.0f * x)); }

// Runtime input-dtype detection: ln_i_w is all ones per reset_parameters.
// fp32 word0 = 0x3F800000 ; bf16 pair word0 = 0x3F803F80.
// R1/R2 A/B test proved inputs are fp32; keep detection as cheap insurance.
__device__ __forceinline__ int detect_fp32(const void* disc) {
  return ((const unsigned int*)disc)[0] == 0x3F800000u;
}
__device__ __forceinline__ float ldf(const void* p, int i, int fp32) {
  return fp32 ? ((const float*)p)[i] : us2f(((const ushort_t*)p)[i]);
}
__device__ __forceinline__ void ld8(const void* p, int idx, float* o, int fp32) {
  if (fp32) {
    const float4* q = (const float4*)((const float*)p + idx);
    float4 v0 = q[0], v1 = q[1];
    o[0]=v0.x; o[1]=v0.y; o[2]=v0.z; o[3]=v0.w;
    o[4]=v1.x; o[5]=v1.y; o[6]=v1.z; o[7]=v1.w;
  } else {
    uint4 v = *(const uint4*)((const ushort_t*)p + idx);
    const ushort_t* pv = (const ushort_t*)&v;
    #pragma unroll
    for (int i = 0; i < 8; i++) o[i] = us2f(pv[i]);
  }
}

// ---------------------------------------------------------------------------
// K2: Wt[f][col] = A[col][f] * ln_w[col]   (A = w_*_a [4096][128])
// ---------------------------------------------------------------------------
__global__ __launch_bounds__(256) void k_transpose(
    const void* __restrict__ A0, const void* __restrict__ A1,
    const void* __restrict__ lnw0, const void* __restrict__ lnw1,
    float* __restrict__ Wt0, float* __restrict__ Wt1)
{
  const void* A   = blockIdx.z ? A1 : A0;
  const void* lnw = blockIdx.z ? lnw1 : lnw0;
  float*      Wt  = blockIdx.z ? Wt1 : Wt0;
  int fp32 = detect_fp32(lnw0);
  __shared__ float tile[32][33];
  int n0 = blockIdx.x * 32, f0 = blockIdx.y * 32;
  int tx = threadIdx.x, ty = threadIdx.y;
  #pragma unroll
  for (int u = 0; u < 4; u++) {
    int nl = ty + 8 * u;
    tile[nl][tx] = ldf(A, (n0 + nl) * F_ + f0 + tx, fp32);
  }
  __syncthreads();
  float lw = ldf(lnw, n0 + tx, fp32);
  #pragma unroll
  for (int u = 0; u < 4; u++) {
    int fl = ty + 8 * u;
    Wt[(f0 + fl) * G4_ + n0 + tx] = tile[tx][fl] * lw;
  }
}

// ---------------------------------------------------------------------------
// K2b: column sums of raw A: cm[f] = sum_n A[n][f]
// ---------------------------------------------------------------------------
__global__ __launch_bounds__(1024) void k_colsum(
    const void* __restrict__ A0, const void* __restrict__ A1,
    const void* __restrict__ disc,
    float* __restrict__ cm0, float* __restrict__ cm1)
{
  const void* A = blockIdx.y ? A1 : A0;
  float* cm = blockIdx.y ? cm1 : cm0;
  int fp32 = detect_fp32(disc);
  int f = threadIdx.x & 127, sub = threadIdx.x >> 7;
  int n0 = (blockIdx.x * 8 + sub) * 64;
  float s = 0.f;
  for (int n = n0; n < n0 + 64; n++) s += ldf(A, n * F_ + f, fp32);
  atomicAdd(&cm[f], s);
}

// ---------------------------------------------------------------------------
// K1: C[b][f] = (sum_k X[b][k] * W[f][k]) * scale(b,f)
// ---------------------------------------------------------------------------
__global__ __launch_bounds__(256) void k_gemm1(
    const void* __restrict__ X0, const void* __restrict__ X1,
    const void* __restrict__ W0, const void* __restrict__ W1,
    const void* __restrict__ topic,
    const void* __restrict__ thw0, const void* __restrict__ thw1,
    const void* __restrict__ thb0, const void* __restrict__ thb1,
    const void* __restrict__ wb0,  const void* __restrict__ wb1,
    const void* __restrict__ disc,
    float* __restrict__ C0, float* __restrict__ C1)
{
  const void* X   = blockIdx.y ? X1 : X0;
  const void* W   = blockIdx.y ? W1 : W0;
  const void* thw = blockIdx.y ? thw1 : thw0;
  const void* thb = blockIdx.y ? thb1 : thb0;
  const void* wb  = blockIdx.y ? wb1 : wb0;
  float* C = blockIdx.y ? C1 : C0;
  int fp32 = detect_fp32(disc);

  __shared__ float Xs[64][36];
  __shared__ float Ws[64][132];
  int tid = threadIdx.x;
  int tx = tid & 31, ty = tid >> 5;
  int b0 = blockIdx.x * 32;
  float acc[4][4] = {};

  for (int k0 = 0; k0 < IN_; k0 += 64) {
    {
      int r = tid >> 3, k8 = (tid & 7) * 8;
      float t[8];
      ld8(X, (b0 + r) * IN_ + k0 + k8, t, fp32);
      #pragma unroll
      for (int i = 0; i < 8; i++) Xs[k8 + i][r] = t[i];
    }
    #pragma unroll
    for (int j = 0; j < 4; j++) {
      int idx = tid + 256 * j;
      int f = idx >> 3, k8 = (idx & 7) * 8;
      float t[8];
      ld8(W, f * IN_ + k0 + k8, t, fp32);
      #pragma unroll
      for (int i = 0; i < 8; i++) Ws[k8 + i][f] = t[i];
    }
    __syncthreads();
    #pragma unroll 4
    for (int kk = 0; kk < 64; kk++) {
      float4 xv = *(const float4*)&Xs[kk][4 * ty];
      float4 wv = *(const float4*)&Ws[kk][4 * tx];
      const float* xa = (const float*)&xv;
      const float* wa = (const float*)&wv;
      #pragma unroll
      for (int i = 0; i < 4; i++)
        #pragma unroll
        for (int j = 0; j < 4; j++) acc[i][j] += xa[i] * wa[j];
    }
    __syncthreads();
  }

  float thwf[3][3], thbf[3];
  #pragma unroll
  for (int t = 0; t < 3; t++) {
    thbf[t] = ldf(thb, t, fp32);
    #pragma unroll
    for (int t2 = 0; t2 < 3; t2++) thwf[t][t2] = ldf(thw, t * 3 + t2, fp32);
  }
  float wbf[4][3];
  #pragma unroll
  for (int j = 0; j < 4; j++)
    #pragma unroll
    for (int t = 0; t < 3; t++) wbf[j][t] = ldf(wb, (4 * tx + j) * 3 + t, fp32);

  #pragma unroll
  for (int i = 0; i < 4; i++) {
    int b = b0 + 4 * ty + i;
    float tp[3];
    #pragma unroll
    for (int t2 = 0; t2 < 3; t2++) tp[t2] = ldf(topic, b * 3 + t2, fp32);
    float tmp[3];
    #pragma unroll
    for (int t = 0; t < 3; t++)
      tmp[t] = thbf[t] + tp[0] * thwf[t][0] + tp[1] * thwf[t][1] + tp[2] * thwf[t][2];
    #pragma unroll
    for (int j = 0; j < 4; j++) {
      float sc = tmp[0] * wbf[j][0] + tmp[1] * wbf[j][1] + tmp[2] * wbf[j][2];
      C[b * F_ + 4 * tx + j] = acc[i][j] * sc;
    }
  }
}

// ---------------------------------------------------------------------------
// K3: Gram G = A^T A  ([128][128]), split-K over n with atomic reduce.
// ---------------------------------------------------------------------------
__global__ __launch_bounds__(256) void k_gram(
    const void* __restrict__ A0, const void* __restrict__ A1,
    const void* __restrict__ disc,
    float* __restrict__ G0, float* __restrict__ G1)
{
  const void* A = blockIdx.y ? A1 : A0;
  float* G = blockIdx.y ? G1 : G0;
  int fp32 = detect_fp32(disc);
  __shared__ float As[32][128];
  int tid = threadIdx.x;
  int f1_0 = blockIdx.x * 32;
  int tf2 = tid & 31, tf1 = tid >> 5;
  float acc[4][4] = {};
  int nbase = blockIdx.z * 256;
  for (int n0 = nbase; n0 < nbase + 256; n0 += 32) {
    #pragma unroll
    for (int j = 0; j < 2; j++) {
      int idx = tid + 256 * j;
      int nn = idx >> 4, f8 = (idx & 15) * 8;
      float t[8];
      ld8(A, (n0 + nn) * F_ + f8, t, fp32);
      #pragma unroll
      for (int i = 0; i < 8; i++) As[nn][f8 + i] = t[i];
    }
    __syncthreads();
    #pragma unroll 4
    for (int nn = 0; nn < 32; nn++) {
      float4 a1 = *(const float4*)&As[nn][f1_0 + 4 * tf1];
      float4 a2 = *(const float4*)&As[nn][4 * tf2];
      const float* x1 = (const float*)&a1;
      const float* x2 = (const float*)&a2;
      #pragma unroll
      for (int i = 0; i < 4; i++)
        #pragma unroll
        for (int j = 0; j < 4; j++) acc[i][j] += x1[i] * x2[j];
    }
    __syncthreads();
  }
  #pragma unroll
  for (int i = 0; i < 4; i++)
    #pragma unroll
    for (int j = 0; j < 4; j++)
      atomicAdd(&G[(f1_0 + 4 * tf1 + i) * F_ + 4 * tf2 + j], acc[i][j]);
}

// ---------------------------------------------------------------------------
// K4: H = C @ G   ([4096][128] @ [128][128])
// ---------------------------------------------------------------------------
__global__ __launch_bounds__(256) void k_gemm2(
    const float* __restrict__ C0, const float* __restrict__ C1,
    const float* __restrict__ Gi, const float* __restrict__ Gh,
    float* __restrict__ H0, float* __restrict__ H1)
{
  const float* C = blockIdx.y ? C1 : C0;
  const float* G = blockIdx.y ? Gh : Gi;
  float* Ho = blockIdx.y ? H1 : H0;
  __shared__ float Xs[32][36];
  __shared__ float Ws[32][132];
  int tid = threadIdx.x, tx = tid & 31, ty = tid >> 5;
  int b0 = blockIdx.x * 32;
  float acc[4][4] = {};
  for (int k0 = 0; k0 < F_; k0 += 32) {
    {
      int r = tid >> 3, k4 = (tid & 7) * 4;
      float4 v = *(const float4*)(C + (b0 + r) * F_ + k0 + k4);
      Xs[k4][r] = v.x; Xs[k4 + 1][r] = v.y; Xs[k4 + 2][r] = v.z; Xs[k4 + 3][r] = v.w;
    }
    #pragma unroll
    for (int j = 0; j < 4; j++) {
      int idx = tid + 256 * j;
      int f = idx >> 3, k4 = (idx & 7) * 4;
      float4 v = *(const float4*)(G + f * F_ + k0 + k4);
      Ws[k4][f] = v.x; Ws[k4 + 1][f] = v.y; Ws[k4 + 2][f] = v.z; Ws[k4 + 3][f] = v.w;
    }
    __syncthreads();
    #pragma unroll 4
    for (int kk = 0; kk < 32; kk++) {
      float4 xv = *(const float4*)&Xs[kk][4 * ty];
      float4 wv = *(const float4*)&Ws[kk][4 * tx];
      const float* xa = (const float*)&xv;
      const float* wa = (const float*)&wv;
      #pragma unroll
      for (int i = 0; i < 4; i++)
        #pragma unroll
        for (int j = 0; j < 4; j++) acc[i][j] += xa[i] * wa[j];
    }
    __syncthreads();
  }
  #pragma unroll
  for (int i = 0; i < 4; i++)
    #pragma unroll
    for (int j = 0; j < 4; j++)
      Ho[(b0 + 4 * ty + i) * F_ + 4 * tx + j] = acc[i][j];
}

// ---------------------------------------------------------------------------
// K5: per-row LN stats via Gram trick + write Ct (rs-scaled, transposed chunks)
// ---------------------------------------------------------------------------
__global__ __launch_bounds__(256) void k_stats(
    const float* __restrict__ Ca, const float* __restrict__ Cb,
    const float* __restrict__ Ha, const float* __restrict__ Hb,
    const float* __restrict__ cma, const float* __restrict__ cmb,
    float* __restrict__ mrsa, float* __restrict__ mrsb,
    float* __restrict__ Cta, float* __restrict__ Ctb)
{
  const float* C  = blockIdx.y ? Cb : Ca;
  const float* Hm = blockIdx.y ? Hb : Ha;
  const float* cm = blockIdx.y ? cmb : cma;
  float* mrs = blockIdx.y ? mrsb : mrsa;
  float* Ct  = blockIdx.y ? Ctb : Cta;

  int tid = threadIdx.x;
  int b0 = blockIdx.x * 16;
  int r = tid >> 4, l = tid & 15;
  __shared__ float rs_s[16];
  int b = b0 + r;
  float p1 = 0.f, p2 = 0.f;
  #pragma unroll
  for (int j = 0; j < 8; j++) {
    int f = l + 16 * j;
    float c = C[b * F_ + f];
    p1 += c * Hm[b * F_ + f];
    p2 += c * cm[f];
  }
  p1 += __shfl_down(p1, 8, 16); p2 += __shfl_down(p2, 8, 16);
  p1 += __shfl_down(p1, 4, 16); p2 += __shfl_down(p2, 4, 16);
  p1 += __shfl_down(p1, 2, 16); p2 += __shfl_down(p2, 2, 16);
  p1 += __shfl_down(p1, 1, 16); p2 += __shfl_down(p2, 1, 16);
  if (l == 0) {
    float E2 = p1 * (1.0f / 4096.0f);
    float mu = p2 * (1.0f / 4096.0f);
    float var = E2 - mu * mu;
    float rs = rsqrtf(var + EPS_);
    rs_s[r] = rs;
    mrs[b] = mu * rs;
  }
  __syncthreads();
  int f = tid & 127, half = tid >> 7;
  float* ct = Ct + (size_t)blockIdx.x * (F_ * 16);
  #pragma unroll
  for (int i = 0; i < 8; i++) {
    int r2 = half * 8 + i;
    ct[f * 16 + r2] = C[(b0 + r2) * F_ + f] * rs_s[r2];
  }
}

// ---------------------------------------------------------------------------
// K6: fused stage-2 (16 rows x 1024 cols per block, 512 threads).
// cy pre-LN kept in registers (fp32); row stats via wave shuffle + LDS
// partials; outputs written as FP32 (R2 evidence: d_out is fp32).
// ---------------------------------------------------------------------------
__global__ __launch_bounds__(512) void k_fused(
    const float* __restrict__ c1t, const float* __restrict__ c2t,
    const float* __restrict__ wti, const float* __restrict__ wth,
    const float* __restrict__ mrs_i, const float* __restrict__ mrs_h,
    const void* __restrict__ lniw, const void* __restrict__ lnib,
    const void* __restrict__ lnhw, const void* __restrict__ lnhb,
    const void* __restrict__ lncw, const void* __restrict__ lncb,
    const void* __restrict__ cx, float* __restrict__ out)
{
  __shared__ float wpart[8][16][2];
  __shared__ float mu_s[16], rs_s[16];
  int tid = threadIdx.x;
  int b0 = blockIdx.x * 16;
  int fp32 = detect_fp32(lniw);
  const float* cA = c1t + (size_t)blockIdx.x * (F_ * 16);
  const float* cB = c2t + (size_t)blockIdx.x * (F_ * 16);
  float val[2][16], o_keep[2][16];

  #pragma unroll
  for (int p = 0; p < 2; p++) {
    int n = tid + 512 * p;
    float acc[4][16] = {};
    #pragma unroll 2
    for (int k = 0; k < F_; k++) {
      float a[16], c[16];
      const float4* pa = (const float4*)(cA + k * 16);
      const float4* pb = (const float4*)(cB + k * 16);
      ((float4*)a)[0] = pa[0]; ((float4*)a)[1] = pa[1];
      ((float4*)a)[2] = pa[2]; ((float4*)a)[3] = pa[3];
      ((float4*)c)[0] = pb[0]; ((float4*)c)[1] = pb[1];
      ((float4*)c)[2] = pb[2]; ((float4*)c)[3] = pb[3];
      float wa[4], wc[4];
      #pragma unroll
      for (int g = 0; g < 4; g++) {
        wa[g] = wti[k * G4_ + g * H_ + n];
        wc[g] = wth[k * G4_ + g * H_ + n];
      }
      #pragma unroll
      for (int g = 0; g < 4; g++)
        #pragma unroll
        for (int r = 0; r < 16; r++)
          acc[g][r] += a[r] * wa[g] + c[r] * wc[g];
    }
    float mi[16], mh[16];
    #pragma unroll
    for (int r = 0; r < 16; r++) { mi[r] = mrs_i[b0 + r]; mh[r] = mrs_h[b0 + r]; }
    #pragma unroll
    for (int g = 0; g < 4; g++) {
      float liw = ldf(lniw, g * H_ + n, fp32);
      float lib = ldf(lnib, g * H_ + n, fp32);
      float lhw = ldf(lnhw, g * H_ + n, fp32);
      float lhb = ldf(lnhb, g * H_ + n, fp32);
      #pragma unroll
      for (int r = 0; r < 16; r++)
        acc[g][r] += lib + lhb - mi[r] * liw - mh[r] * lhw;
    }
    #pragma unroll
    for (int r = 0; r < 16; r++) {
      float iv = sigf(acc[0][r]);
      float fv = sigf(acc[1][r]);
      float gv = tanh_f(acc[2][r]);
      float ov = sigf(acc[3][r]);
      float cxv = ldf(cx, (b0 + r) * H_ + n, fp32);
      val[p][r] = fv * cxv + iv * gv;
      o_keep[p][r] = ov;
    }
  }

  // row-wise LN stats over n: per-thread partials -> wave shuffle -> LDS
  float s1[16], s2[16];
  #pragma unroll
  for (int r = 0; r < 16; r++) {
    s1[r] = val[0][r] + val[1][r];
    s2[r] = val[0][r] * val[0][r] + val[1][r] * val[1][r];
  }
  #pragma unroll
  for (int d = 32; d >= 1; d >>= 1) {
    #pragma unroll
    for (int r = 0; r < 16; r++) {
      s1[r] += __shfl_down(s1[r], d, 64);
      s2[r] += __shfl_down(s2[r], d, 64);
    }
  }
  int wv = tid >> 6, lane = tid & 63;
  if (lane == 0) {
    #pragma unroll
    for (int r = 0; r < 16; r++) {
      wpart[wv][r][0] = s1[r];
      wpart[wv][r][1] = s2[r];
    }
  }
  __syncthreads();
  if (tid < 16) {
    float t1 = 0.f, t2 = 0.f;
    #pragma unroll
    for (int w = 0; w < 8; w++) { t1 += wpart[w][tid][0]; t2 += wpart[w][tid][1]; }
    float mu = t1 * (1.0f / 1024.0f);
    float var = t2 * (1.0f / 1024.0f) - mu * mu;
    mu_s[tid] = mu;
    rs_s[tid] = rsqrtf(var + EPS_);
  }
  __syncthreads();
  #pragma unroll
  for (int p = 0; p < 2; p++) {
    int n = tid + 512 * p;
    float lw = ldf(lncw, n, fp32), lb = ldf(lncb, n, fp32);
    #pragma unroll
    for (int r = 0; r < 16; r++) {
      float cyv = (val[p][r] - mu_s[r]) * rs_s[r] * lw + lb;
      float hyv = o_keep[p][r] * tanh_f(cyv);
      out[(b0 + r) * H_ + n] = hyv;
      out[B_ * H_ + (b0 + r) * H_ + n] = cyv;
    }
  }
}

// ---------------------------------------------------------------------------
extern "C" void kernel_launch(void* const* d_in, const int* in_sizes, int n_in,
                              void* d_out, int out_size, void* d_ws, size_t ws_size,
                              hipStream_t stream) {
  const void* input_  = d_in[0];
  const void* hx      = d_in[1];
  const void* cx      = d_in[2];
  const void* topic   = d_in[3];
  const void* w_ih_a  = d_in[4];
  const void* w_ih_b  = d_in[5];
  const void* w_ih_c  = d_in[6];
  const void* w_hh_a  = d_in[7];
  const void* w_hh_b  = d_in[8];
  const void* w_hh_c  = d_in[9];
  const void* th_ih_w = d_in[10];
  const void* th_ih_b = d_in[11];
  const void* th_hh_w = d_in[12];
  const void* th_hh_b = d_in[13];
  const void* ln_i_w  = d_in[14];
  const void* ln_i_b  = d_in[15];
  const void* ln_h_w  = d_in[16];
  const void* ln_h_b  = d_in[17];
  const void* ln_c_w  = d_in[18];
  const void* ln_c_b  = d_in[19];

  float* w = (float*)d_ws;
  float* c1    = w;
  float* c2    = c1 + B_ * F_;
  float* h1    = c2 + B_ * F_;
  float* h2    = h1 + B_ * F_;
  float* c1t   = h2 + B_ * F_;
  float* c2t   = c1t + F_ * B_;
  float* wti   = c2t + F_ * B_;
  float* wth   = wti + F_ * G4_;
  float* g_i   = wth + F_ * G4_;
  float* g_h   = g_i + F_ * F_;
  float* cm_i  = g_h + F_ * F_;
  float* cm_h  = cm_i + F_;
  float* mrs_i = cm_h + F_;
  float* mrs_h = mrs_i + B_;

  hipMemsetAsync(g_i, 0, (size_t)(2 * F_ * F_ + 2 * F_) * sizeof(float), stream);

  k_transpose<<<dim3(128, 4, 2), dim3(32, 8), 0, stream>>>(
      w_ih_a, w_hh_a, ln_i_w, ln_h_w, wti, wth);
  k_colsum<<<dim3(8, 2), dim3(1024), 0, stream>>>(w_ih_a, w_hh_a, ln_i_w, cm_i, cm_h);
  k_gemm1<<<dim3(128, 2), dim3(256), 0, stream>>>(
      input_, hx, w_ih_c, w_hh_c, topic,
      th_ih_w, th_hh_w, th_ih_b, th_hh_b, w_ih_b, w_hh_b, ln_i_w, c1, c2);
  k_gram<<<dim3(4, 2, 16), dim3(256), 0, stream>>>(w_ih_a, w_hh_a, ln_i_w, g_i, g_h);
  k_gemm2<<<dim3(128, 2), dim3(256), 0, stream>>>(c1, c2, g_i, g_h, h1, h2);
  k_stats<<<dim3(256, 2), dim3(256), 0, stream>>>(
      c1, c2, h1, h2, cm_i, cm_h, mrs_i, mrs_h, c1t, c2t);
  k_fused<<<dim3(256), dim3(512), 0, stream>>>(
      c1t, c2t, wti, wth, mrs_i, mrs_h,
      ln_i_w, ln_i_b, ln_h_w, ln_h_b, ln_c_w, ln_c_b, cx, (float*)d_out);
}

// Round 4
// 352.645 us; speedup vs baseline: 1.1609x; 1.1609x over previous
//
#include <hip/hip_runtime.h>

typedef unsigned short ushort_t;
typedef __attribute__((ext_vector_type(8))) short bf8_t;   // 8 x bf16 (4 VGPRs)
typedef __attribute__((ext_vector_type(4))) float f4_t;    // MFMA acc

#define B_   4096
#define IN_  1024
#define H_   1024
#define F_   128
#define G4_  4096
#define EPS_ 1e-5f

__device__ __forceinline__ float us2f(unsigned short s) {
  union { unsigned int u; float f; } v;
  v.u = ((unsigned int)s) << 16;
  return v.f;
}
__device__ __forceinline__ unsigned short f2us(float f) {  // fp32 -> bf16 RNE
  union { float f; unsigned int u; } v;
  v.f = f;
  unsigned int r = (v.u + 0x7fffu + ((v.u >> 16) & 1u)) >> 16;
  return (unsigned short)r;
}
__device__ __forceinline__ float sigf(float x) { return 1.0f / (1.0f + __expf(-x)); }
__device__ __forceinline__ float tanh_f(float x) { return 1.0f - 2.0f / (1.0f + __expf(2.0f * x)); }

// Runtime input-dtype detection (R1/R2 A/B proved fp32; keep as insurance).
__device__ __forceinline__ int detect_fp32(const void* disc) {
  return ((const unsigned int*)disc)[0] == 0x3F800000u;
}
__device__ __forceinline__ float ldf(const void* p, int i, int fp32) {
  return fp32 ? ((const float*)p)[i] : us2f(((const ushort_t*)p)[i]);
}
__device__ __forceinline__ void ld8(const void* p, int idx, float* o, int fp32) {
  if (fp32) {
    const float4* q = (const float4*)((const float*)p + idx);
    float4 v0 = q[0], v1 = q[1];
    o[0]=v0.x; o[1]=v0.y; o[2]=v0.z; o[3]=v0.w;
    o[4]=v1.x; o[5]=v1.y; o[6]=v1.z; o[7]=v1.w;
  } else {
    uint4 v = *(const uint4*)((const ushort_t*)p + idx);
    const ushort_t* pv = (const ushort_t*)&v;
    #pragma unroll
    for (int i = 0; i < 8; i++) o[i] = us2f(pv[i]);
  }
}

// ---------------------------------------------------------------------------
// K_prepw: W[k][n] (K=256, N=4096) in bf16 B-fragment order.
//   k<128: w_ih_a[n][k]*ln_i_w[n];  k>=128: w_hh_a[n][k-128]*ln_h_w[n]
// Fragment order: wb[t*4096 + c*512 + l*8 + j] = W[c*32+(l>>4)*8+j][t*16+(l&15)]
// ---------------------------------------------------------------------------
__global__ __launch_bounds__(256) void k_prepw(
    const void* __restrict__ Ai, const void* __restrict__ Ah,
    const void* __restrict__ lnwi, const void* __restrict__ lnwh,
    ushort_t* __restrict__ wb)
{
  int t = blockIdx.x, tid = threadIdx.x;
  int fp32 = detect_fp32(lnwi);
  #pragma unroll
  for (int i = 0; i < 16; i++) {
    int e = i * 256 + tid;
    int c = e >> 9, l = (e >> 3) & 63, j = e & 7;
    int k = c * 32 + ((l >> 4) << 3) + j;
    int n = t * 16 + (l & 15);
    float v;
    if (k < 128) v = ldf(Ai, n * F_ + k, fp32) * ldf(lnwi, n, fp32);
    else         v = ldf(Ah, n * F_ + (k - 128), fp32) * ldf(lnwh, n, fp32);
    wb[(size_t)t * 4096 + e] = f2us(v);
  }
}

// ---------------------------------------------------------------------------
// K2b: column sums of raw A: cm[f] = sum_n A[n][f]
// ---------------------------------------------------------------------------
__global__ __launch_bounds__(1024) void k_colsum(
    const void* __restrict__ A0, const void* __restrict__ A1,
    const void* __restrict__ disc,
    float* __restrict__ cm0, float* __restrict__ cm1)
{
  const void* A = blockIdx.y ? A1 : A0;
  float* cm = blockIdx.y ? cm1 : cm0;
  int fp32 = detect_fp32(disc);
  int f = threadIdx.x & 127, sub = threadIdx.x >> 7;
  int n0 = (blockIdx.x * 8 + sub) * 64;
  float s = 0.f;
  for (int n = n0; n < n0 + 64; n++) s += ldf(A, n * F_ + f, fp32);
  atomicAdd(&cm[f], s);
}

// ---------------------------------------------------------------------------
// K1: C[b][f] = (sum_k X[b][k] * W[f][k]) * scale(b,f)
// ---------------------------------------------------------------------------
__global__ __launch_bounds__(256) void k_gemm1(
    const void* __restrict__ X0, const void* __restrict__ X1,
    const void* __restrict__ W0, const void* __restrict__ W1,
    const void* __restrict__ topic,
    const void* __restrict__ thw0, const void* __restrict__ thw1,
    const void* __restrict__ thb0, const void* __restrict__ thb1,
    const void* __restrict__ wb0,  const void* __restrict__ wb1,
    const void* __restrict__ disc,
    float* __restrict__ C0, float* __restrict__ C1)
{
  const void* X   = blockIdx.y ? X1 : X0;
  const void* W   = blockIdx.y ? W1 : W0;
  const void* thw = blockIdx.y ? thw1 : thw0;
  const void* thb = blockIdx.y ? thb1 : thb0;
  const void* wb  = blockIdx.y ? wb1 : wb0;
  float* C = blockIdx.y ? C1 : C0;
  int fp32 = detect_fp32(disc);

  __shared__ float Xs[64][36];
  __shared__ float Ws[64][132];
  int tid = threadIdx.x;
  int tx = tid & 31, ty = tid >> 5;
  int b0 = blockIdx.x * 32;
  float acc[4][4] = {};

  for (int k0 = 0; k0 < IN_; k0 += 64) {
    {
      int r = tid >> 3, k8 = (tid & 7) * 8;
      float t[8];
      ld8(X, (b0 + r) * IN_ + k0 + k8, t, fp32);
      #pragma unroll
      for (int i = 0; i < 8; i++) Xs[k8 + i][r] = t[i];
    }
    #pragma unroll
    for (int j = 0; j < 4; j++) {
      int idx = tid + 256 * j;
      int f = idx >> 3, k8 = (idx & 7) * 8;
      float t[8];
      ld8(W, f * IN_ + k0 + k8, t, fp32);
      #pragma unroll
      for (int i = 0; i < 8; i++) Ws[k8 + i][f] = t[i];
    }
    __syncthreads();
    #pragma unroll 4
    for (int kk = 0; kk < 64; kk++) {
      float4 xv = *(const float4*)&Xs[kk][4 * ty];
      float4 wv = *(const float4*)&Ws[kk][4 * tx];
      const float* xa = (const float*)&xv;
      const float* wa = (const float*)&wv;
      #pragma unroll
      for (int i = 0; i < 4; i++)
        #pragma unroll
        for (int j = 0; j < 4; j++) acc[i][j] += xa[i] * wa[j];
    }
    __syncthreads();
  }

  float thwf[3][3], thbf[3];
  #pragma unroll
  for (int t = 0; t < 3; t++) {
    thbf[t] = ldf(thb, t, fp32);
    #pragma unroll
    for (int t2 = 0; t2 < 3; t2++) thwf[t][t2] = ldf(thw, t * 3 + t2, fp32);
  }
  float wbf[4][3];
  #pragma unroll
  for (int j = 0; j < 4; j++)
    #pragma unroll
    for (int t = 0; t < 3; t++) wbf[j][t] = ldf(wb, (4 * tx + j) * 3 + t, fp32);

  #pragma unroll
  for (int i = 0; i < 4; i++) {
    int b = b0 + 4 * ty + i;
    float tp[3];
    #pragma unroll
    for (int t2 = 0; t2 < 3; t2++) tp[t2] = ldf(topic, b * 3 + t2, fp32);
    float tmp[3];
    #pragma unroll
    for (int t = 0; t < 3; t++)
      tmp[t] = thbf[t] + tp[0] * thwf[t][0] + tp[1] * thwf[t][1] + tp[2] * thwf[t][2];
    #pragma unroll
    for (int j = 0; j < 4; j++) {
      float sc = tmp[0] * wbf[j][0] + tmp[1] * wbf[j][1] + tmp[2] * wbf[j][2];
      C[b * F_ + 4 * tx + j] = acc[i][j] * sc;
    }
  }
}

// ---------------------------------------------------------------------------
// K3: Gram G = A^T A  ([128][128]), split-K over n with atomic reduce.
// ---------------------------------------------------------------------------
__global__ __launch_bounds__(256) void k_gram(
    const void* __restrict__ A0, const void* __restrict__ A1,
    const void* __restrict__ disc,
    float* __restrict__ G0, float* __restrict__ G1)
{
  const void* A = blockIdx.y ? A1 : A0;
  float* G = blockIdx.y ? G1 : G0;
  int fp32 = detect_fp32(disc);
  __shared__ float As[32][128];
  int tid = threadIdx.x;
  int f1_0 = blockIdx.x * 32;
  int tf2 = tid & 31, tf1 = tid >> 5;
  float acc[4][4] = {};
  int nbase = blockIdx.z * 256;
  for (int n0 = nbase; n0 < nbase + 256; n0 += 32) {
    #pragma unroll
    for (int j = 0; j < 2; j++) {
      int idx = tid + 256 * j;
      int nn = idx >> 4, f8 = (idx & 15) * 8;
      float t[8];
      ld8(A, (n0 + nn) * F_ + f8, t, fp32);
      #pragma unroll
      for (int i = 0; i < 8; i++) As[nn][f8 + i] = t[i];
    }
    __syncthreads();
    #pragma unroll 4
    for (int nn = 0; nn < 32; nn++) {
      float4 a1 = *(const float4*)&As[nn][f1_0 + 4 * tf1];
      float4 a2 = *(const float4*)&As[nn][4 * tf2];
      const float* x1 = (const float*)&a1;
      const float* x2 = (const float*)&a2;
      #pragma unroll
      for (int i = 0; i < 4; i++)
        #pragma unroll
        for (int j = 0; j < 4; j++) acc[i][j] += x1[i] * x2[j];
    }
    __syncthreads();
  }
  #pragma unroll
  for (int i = 0; i < 4; i++)
    #pragma unroll
    for (int j = 0; j < 4; j++)
      atomicAdd(&G[(f1_0 + 4 * tf1 + i) * F_ + 4 * tf2 + j], acc[i][j]);
}

// ---------------------------------------------------------------------------
// K4: H = C @ G   ([4096][128] @ [128][128])
// ---------------------------------------------------------------------------
__global__ __launch_bounds__(256) void k_gemm2(
    const float* __restrict__ C0, const float* __restrict__ C1,
    const float* __restrict__ Gi, const float* __restrict__ Gh,
    float* __restrict__ H0, float* __restrict__ H1)
{
  const float* C = blockIdx.y ? C1 : C0;
  const float* G = blockIdx.y ? Gh : Gi;
  float* Ho = blockIdx.y ? H1 : H0;
  __shared__ float Xs[32][36];
  __shared__ float Ws[32][132];
  int tid = threadIdx.x, tx = tid & 31, ty = tid >> 5;
  int b0 = blockIdx.x * 32;
  float acc[4][4] = {};
  for (int k0 = 0; k0 < F_; k0 += 32) {
    {
      int r = tid >> 3, k4 = (tid & 7) * 4;
      float4 v = *(const float4*)(C + (b0 + r) * F_ + k0 + k4);
      Xs[k4][r] = v.x; Xs[k4 + 1][r] = v.y; Xs[k4 + 2][r] = v.z; Xs[k4 + 3][r] = v.w;
    }
    #pragma unroll
    for (int j = 0; j < 4; j++) {
      int idx = tid + 256 * j;
      int f = idx >> 3, k4 = (idx & 7) * 4;
      float4 v = *(const float4*)(G + f * F_ + k0 + k4);
      Ws[k4][f] = v.x; Ws[k4 + 1][f] = v.y; Ws[k4 + 2][f] = v.z; Ws[k4 + 3][f] = v.w;
    }
    __syncthreads();
    #pragma unroll 4
    for (int kk = 0; kk < 32; kk++) {
      float4 xv = *(const float4*)&Xs[kk][4 * ty];
      float4 wv = *(const float4*)&Ws[kk][4 * tx];
      const float* xa = (const float*)&xv;
      const float* wa = (const float*)&wv;
      #pragma unroll
      for (int i = 0; i < 4; i++)
        #pragma unroll
        for (int j = 0; j < 4; j++) acc[i][j] += xa[i] * wa[j];
    }
    __syncthreads();
  }
  #pragma unroll
  for (int i = 0; i < 4; i++)
    #pragma unroll
    for (int j = 0; j < 4; j++)
      Ho[(b0 + 4 * ty + i) * F_ + 4 * tx + j] = acc[i][j];
}

// ---------------------------------------------------------------------------
// K5: per-row LN stats via Gram trick; write X in bf16 A-fragment order.
//   xb[blk*4096 + c*512 + l*8 + j] = rs[m]*C[b0+m][f],
//   m=l&15, k = (y?128:0)+f = c*32+(l>>4)*8+j
// ---------------------------------------------------------------------------
__global__ __launch_bounds__(256) void k_stats(
    const float* __restrict__ Ca, const float* __restrict__ Cb,
    const float* __restrict__ Ha, const float* __restrict__ Hb,
    const float* __restrict__ cma, const float* __restrict__ cmb,
    float* __restrict__ mrsa, float* __restrict__ mrsb,
    ushort_t* __restrict__ xb)
{
  const float* C  = blockIdx.y ? Cb : Ca;
  const float* Hm = blockIdx.y ? Hb : Ha;
  const float* cm = blockIdx.y ? cmb : cma;
  float* mrs = blockIdx.y ? mrsb : mrsa;
  int kbase = blockIdx.y ? 128 : 0;

  int tid = threadIdx.x;
  int b0 = blockIdx.x * 16;
  int r = tid >> 4, l = tid & 15;
  __shared__ float rs_s[16];
  int b = b0 + r;
  float p1 = 0.f, p2 = 0.f;
  #pragma unroll
  for (int j = 0; j < 8; j++) {
    int f = l + 16 * j;
    float c = C[b * F_ + f];
    p1 += c * Hm[b * F_ + f];
    p2 += c * cm[f];
  }
  p1 += __shfl_down(p1, 8, 16); p2 += __shfl_down(p2, 8, 16);
  p1 += __shfl_down(p1, 4, 16); p2 += __shfl_down(p2, 4, 16);
  p1 += __shfl_down(p1, 2, 16); p2 += __shfl_down(p2, 2, 16);
  p1 += __shfl_down(p1, 1, 16); p2 += __shfl_down(p2, 1, 16);
  if (l == 0) {
    float E2 = p1 * (1.0f / 4096.0f);
    float mu = p2 * (1.0f / 4096.0f);
    float var = E2 - mu * mu;
    float rs = rsqrtf(var + EPS_);
    rs_s[r] = rs;
    mrs[b] = mu * rs;
  }
  __syncthreads();
  int f = tid & 127, half = tid >> 7;
  ushort_t* xbb = xb + (size_t)blockIdx.x * 4096;
  int k = kbase + f;
  int c = k >> 5, lq = (k >> 3) & 3, j = k & 7;
  #pragma unroll
  for (int i = 0; i < 8; i++) {
    int r2 = half * 8 + i;                      // m = r2
    int lfrag = r2 | (lq << 4);
    xbb[c * 512 + lfrag * 8 + j] = f2us(C[(b0 + r2) * F_ + f] * rs_s[r2]);
  }
}

// ---------------------------------------------------------------------------
// K6 v2 (MFMA): 16 rows x 1024 cy-cols per block, 512 thr = 8 waves.
// Wave w owns cols [w*128, w*128+128). For each 16-col group q: 4 gate tiles
// (t = g*64 + w*8 + q), each = 8x mfma_f32_16x16x32_bf16 over K=256.
// A-frags register-cached; B streamed from wb (L2-resident, 2 MB).
// C/D layout (m89): col=lane&15, row=(lane>>4)*4+reg.
// ---------------------------------------------------------------------------
__global__ __launch_bounds__(512) void k_fused(
    const ushort_t* __restrict__ xb, const ushort_t* __restrict__ wb,
    const float* __restrict__ mrs_i, const float* __restrict__ mrs_h,
    const void* __restrict__ lniw, const void* __restrict__ lnib,
    const void* __restrict__ lnhw, const void* __restrict__ lnhb,
    const void* __restrict__ lncw, const void* __restrict__ lncb,
    const void* __restrict__ cx, float* __restrict__ out)
{
  __shared__ float wpart[8][16][2];
  __shared__ float mu_s[16], rs_s[16];
  int tid = threadIdx.x;
  int lane = tid & 63, w = tid >> 6;
  int quad = lane >> 4, lcol = lane & 15;
  int b0 = blockIdx.x * 16;
  int fp32 = detect_fp32(lniw);

  // A-fragments for this block's 16 rows (shared by all waves)
  const ushort_t* xblk = xb + (size_t)blockIdx.x * 4096;
  bf8_t af[8];
  #pragma unroll
  for (int c = 0; c < 8; c++)
    af[c] = *(const bf8_t*)(xblk + c * 512 + lane * 8);

  float mi[4], mh[4];
  #pragma unroll
  for (int reg = 0; reg < 4; reg++) {
    mi[reg] = mrs_i[b0 + quad * 4 + reg];
    mh[reg] = mrs_h[b0 + quad * 4 + reg];
  }

  float val[8][4], okeep[8][4];
  int colbase = w * 128;

  #pragma unroll 2
  for (int q = 0; q < 8; q++) {
    int col = colbase + q * 16 + lcol;
    f4_t accg[4];
    #pragma unroll
    for (int g = 0; g < 4; g++) {
      f4_t acc = {0.f, 0.f, 0.f, 0.f};
      int t = g * 64 + w * 8 + q;
      const ushort_t* wt = wb + (size_t)t * 4096 + lane * 8;
      #pragma unroll
      for (int c = 0; c < 8; c++) {
        bf8_t bf = *(const bf8_t*)(wt + c * 512);
        acc = __builtin_amdgcn_mfma_f32_16x16x32_bf16(af[c], bf, acc, 0, 0, 0);
      }
      accg[g] = acc;
    }
    // epilogue constants per gate for this col
    float liw0 = ldf(lniw, 0 * H_ + col, fp32), lib0 = ldf(lnib, 0 * H_ + col, fp32);
    float lhw0 = ldf(lnhw, 0 * H_ + col, fp32), lhb0 = ldf(lnhb, 0 * H_ + col, fp32);
    float liw1 = ldf(lniw, 1 * H_ + col, fp32), lib1 = ldf(lnib, 1 * H_ + col, fp32);
    float lhw1 = ldf(lnhw, 1 * H_ + col, fp32), lhb1 = ldf(lnhb, 1 * H_ + col, fp32);
    float liw2 = ldf(lniw, 2 * H_ + col, fp32), lib2 = ldf(lnib, 2 * H_ + col, fp32);
    float lhw2 = ldf(lnhw, 2 * H_ + col, fp32), lhb2 = ldf(lnhb, 2 * H_ + col, fp32);
    float liw3 = ldf(lniw, 3 * H_ + col, fp32), lib3 = ldf(lnib, 3 * H_ + col, fp32);
    float lhw3 = ldf(lnhw, 3 * H_ + col, fp32), lhb3 = ldf(lnhb, 3 * H_ + col, fp32);
    #pragma unroll
    for (int reg = 0; reg < 4; reg++) {
      int m = quad * 4 + reg;
      float gi = accg[0][reg] + lib0 + lhb0 - mi[reg] * liw0 - mh[reg] * lhw0;
      float gf = accg[1][reg] + lib1 + lhb1 - mi[reg] * liw1 - mh[reg] * lhw1;
      float gg = accg[2][reg] + lib2 + lhb2 - mi[reg] * liw2 - mh[reg] * lhw2;
      float go = accg[3][reg] + lib3 + lhb3 - mi[reg] * liw3 - mh[reg] * lhw3;
      float iv = sigf(gi), fv = sigf(gf), gv = tanh_f(gg), ov = sigf(go);
      float cxv = ldf(cx, (b0 + m) * H_ + col, fp32);
      val[q][reg] = fv * cxv + iv * gv;
      okeep[q][reg] = ov;
    }
  }

  // cy-LN stats: per-lane partials over q, reduce across 16 lanes of quad group
  float s1[4] = {}, s2[4] = {};
  #pragma unroll
  for (int q = 0; q < 8; q++)
    #pragma unroll
    for (int reg = 0; reg < 4; reg++) {
      s1[reg] += val[q][reg];
      s2[reg] += val[q][reg] * val[q][reg];
    }
  #pragma unroll
  for (int d = 1; d < 16; d <<= 1) {
    #pragma unroll
    for (int reg = 0; reg < 4; reg++) {
      s1[reg] += __shfl_xor(s1[reg], d, 64);
      s2[reg] += __shfl_xor(s2[reg], d, 64);
    }
  }
  if (lcol == 0) {
    #pragma unroll
    for (int reg = 0; reg < 4; reg++) {
      wpart[w][quad * 4 + reg][0] = s1[reg];
      wpart[w][quad * 4 + reg][1] = s2[reg];
    }
  }
  __syncthreads();
  if (tid < 16) {
    float t1 = 0.f, t2 = 0.f;
    #pragma unroll
    for (int ww = 0; ww < 8; ww++) { t1 += wpart[ww][tid][0]; t2 += wpart[ww][tid][1]; }
    float mu = t1 * (1.0f / 1024.0f);
    float var = t2 * (1.0f / 1024.0f) - mu * mu;
    mu_s[tid] = mu;
    rs_s[tid] = rsqrtf(var + EPS_);
  }
  __syncthreads();

  #pragma unroll 2
  for (int q = 0; q < 8; q++) {
    int col = colbase + q * 16 + lcol;
    float lw = ldf(lncw, col, fp32), lb = ldf(lncb, col, fp32);
    #pragma unroll
    for (int reg = 0; reg < 4; reg++) {
      int m = quad * 4 + reg;
      float cyv = (val[q][reg] - mu_s[m]) * rs_s[m] * lw + lb;
      float hyv = okeep[q][reg] * tanh_f(cyv);
      out[(b0 + m) * H_ + col] = hyv;
      out[(size_t)B_ * H_ + (b0 + m) * H_ + col] = cyv;
    }
  }
}

// ---------------------------------------------------------------------------
extern "C" void kernel_launch(void* const* d_in, const int* in_sizes, int n_in,
                              void* d_out, int out_size, void* d_ws, size_t ws_size,
                              hipStream_t stream) {
  const void* input_  = d_in[0];
  const void* hx      = d_in[1];
  const void* cx      = d_in[2];
  const void* topic   = d_in[3];
  const void* w_ih_a  = d_in[4];
  const void* w_ih_b  = d_in[5];
  const void* w_ih_c  = d_in[6];
  const void* w_hh_a  = d_in[7];
  const void* w_hh_b  = d_in[8];
  const void* w_hh_c  = d_in[9];
  const void* th_ih_w = d_in[10];
  const void* th_ih_b = d_in[11];
  const void* th_hh_w = d_in[12];
  const void* th_hh_b = d_in[13];
  const void* ln_i_w  = d_in[14];
  const void* ln_i_b  = d_in[15];
  const void* ln_h_w  = d_in[16];
  const void* ln_h_b  = d_in[17];
  const void* ln_c_w  = d_in[18];
  const void* ln_c_b  = d_in[19];

  float* w = (float*)d_ws;
  float* c1    = w;                          // B*F
  float* c2    = c1 + B_ * F_;
  float* h1    = c2 + B_ * F_;
  float* h2    = h1 + B_ * F_;
  float* g_i   = h2 + B_ * F_;               // F*F
  float* g_h   = g_i + F_ * F_;
  float* cm_i  = g_h + F_ * F_;              // F
  float* cm_h  = cm_i + F_;
  float* mrs_i = cm_h + F_;                  // B
  float* mrs_h = mrs_i + B_;
  ushort_t* xb = (ushort_t*)(mrs_h + B_);    // B*256 bf16 (A-frag order)
  ushort_t* wbf = xb + (size_t)B_ * 256;     // 256*4096 bf16 (B-frag order)

  hipMemsetAsync(g_i, 0, (size_t)(2 * F_ * F_ + 2 * F_) * sizeof(float), stream);

  k_prepw<<<dim3(256), dim3(256), 0, stream>>>(w_ih_a, w_hh_a, ln_i_w, ln_h_w, wbf);
  k_colsum<<<dim3(8, 2), dim3(1024), 0, stream>>>(w_ih_a, w_hh_a, ln_i_w, cm_i, cm_h);
  k_gemm1<<<dim3(128, 2), dim3(256), 0, stream>>>(
      input_, hx, w_ih_c, w_hh_c, topic,
      th_ih_w, th_hh_w, th_ih_b, th_hh_b, w_ih_b, w_hh_b, ln_i_w, c1, c2);
  k_gram<<<dim3(4, 2, 16), dim3(256), 0, stream>>>(w_ih_a, w_hh_a, ln_i_w, g_i, g_h);
  k_gemm2<<<dim3(128, 2), dim3(256), 0, stream>>>(c1, c2, g_i, g_h, h1, h2);
  k_stats<<<dim3(256, 2), dim3(256), 0, stream>>>(
      c1, c2, h1, h2, cm_i, cm_h, mrs_i, mrs_h, xb);
  k_fused<<<dim3(256), dim3(512), 0, stream>>>(
      xb, wbf, mrs_i, mrs_h,
      ln_i_w, ln_i_b, ln_h_w, ln_h_b, ln_c_w, ln_c_b, cx, (float*)d_out);
}